// Round 5
// baseline (359.982 us; speedup 1.0000x reference)
//
#include <hip/hip_runtime.h>
#include <hip/hip_bf16.h>
#include <cfloat>

// B=32, N=2048 -> BN=65536 rows, D=128, K=1024 codes
#define DIM 128
#define NCODES 1024
#define MTILE 128          // rows per block
#define ROWS_PER_WAVE 32   // per wave (4 row-waves x 2 K-halves = 8 waves)
#define NSUB 2             // 16-row M-subtiles per wave
#define KSTEPS 4           // K=128 / 32
#define GROUPS (NCODES / 16)      // 64 groups of 16 codes
#define HGROUPS (GROUPS / 2)      // 32 groups per K-half
#define LOSS_SCALE (12.5f / 8388608.0f)

typedef _Float16 f16x8 __attribute__((ext_vector_type(8)));
typedef float f32x4 __attribute__((ext_vector_type(4)));

// prep: E (fp32) -> Ehi,Elo (f16 split) + enorm = ||E_k||^2; block 0 zeroes loss
__global__ __launch_bounds__(128) void prep_kernel(const float* __restrict__ E,
                                                   _Float16* __restrict__ Ehi,
                                                   _Float16* __restrict__ Elo,
                                                   float* __restrict__ enorm,
                                                   float* __restrict__ loss) {
    const int k = blockIdx.x;
    const int d = threadIdx.x;
    if (k == 0 && d == 0) *loss = 0.f;
    float e = E[k * DIM + d];
    _Float16 h = (_Float16)e;
    Ehi[k * DIM + d] = h;
    Elo[k * DIM + d] = (_Float16)(e - (float)h);
    float sq = e * e;
#pragma unroll
    for (int off = 32; off > 0; off >>= 1) sq += __shfl_down(sq, off, 64);
    __shared__ float s2[2];
    if ((d & 63) == 0) s2[d >> 6] = sq;
    __syncthreads();
    if (d == 0) enorm[k] = s2[0] + s2[1];
}

// Fused MFMA dist + argmin + gather + loss, in-block K-split.
// 512 threads = 8 waves: wave = 4*khalf + mw. Row-wave mw handles rows
// [mw*32, mw*32+32); K-half khalf handles codes [khalf*512, khalf*512+512).
// 16 waves/CU (vs 8 in r4) doubles latency hiding — r4 was grid-capped at
// 2 waves/SIMD with all pipes <15% busy (latency-bound).
// dist'(m,k) = ||E_k||^2 - 2 z.E_k: acc chains run hh and (hl+lh) with C init 0;
// ||E||^2 added after the chain (keeps the s_enorm LDS read off the MFMA
// critical path). lo*lo term dropped (~2^-22 rel). Ping-pong B registers are
// statically named (r3 lesson: runtime-indexed reg arrays -> scratch).
__global__ __launch_bounds__(512, 4) void vq_kernel(const float* __restrict__ z,
                                                    const _Float16* __restrict__ Ehi,
                                                    const _Float16* __restrict__ Elo,
                                                    const float* __restrict__ enorm,
                                                    const float* __restrict__ E,
                                                    float* __restrict__ out,
                                                    float* __restrict__ loss) {
    const int t = threadIdx.x;
    const int lane = t & 63;
    const int wave = t >> 6;
    const int mw = wave & 3;     // row-wave
    const int khalf = wave >> 2; // code-half
    const int m16 = lane & 15;   // A row within subtile / B,C code col
    const int quad = lane >> 4;  // k-group for A/B; row-group for C

    __shared__ float s_enorm[NCODES];
    __shared__ float s_znorm[MTILE];
    __shared__ float s_bv[MTILE][33];
    __shared__ int s_bi[MTILE][33];
    __shared__ int s_ind[MTILE];
    __shared__ float s_wsum[8];

    for (int i = t; i < NCODES; i += 512) s_enorm[i] = enorm[i];

    // ---- A fragments: wave's 32 rows, K=128, scaled by -2, f16 hi/lo split.
    // A layout (16x16x32): lane holds A[m=lane&15][k=quad*8+j], j=0..7.
    f16x8 Ahi[NSUB][KSTEPS], Alo[NSUB][KSTEPS];
    float znp[NSUB] = {0.f, 0.f};
    const int rowbase = blockIdx.x * MTILE + mw * ROWS_PER_WAVE;
#pragma unroll
    for (int s = 0; s < NSUB; ++s) {
        const int row = rowbase + s * 16 + m16;
        const float* zp = z + (size_t)row * DIM + quad * 8;
#pragma unroll
        for (int ks = 0; ks < KSTEPS; ++ks) {
            float4 v0 = *(const float4*)(zp + ks * 32);
            float4 v1 = *(const float4*)(zp + ks * 32 + 4);
            float zv[8] = {v0.x, v0.y, v0.z, v0.w, v1.x, v1.y, v1.z, v1.w};
#pragma unroll
            for (int j = 0; j < 8; ++j) {
                znp[s] = fmaf(zv[j], zv[j], znp[s]);
                float tt = -2.f * zv[j];
                _Float16 h = (_Float16)tt;
                Ahi[s][ks][j] = h;
                Alo[s][ks][j] = (_Float16)(tt - (float)h);
            }
        }
    }
    // znorm: sum the 4 k-quads. Both khalves compute identical values; the
    // duplicate LDS write is benign (same bits).
#pragma unroll
    for (int s = 0; s < NSUB; ++s) {
        float v = znp[s];
        v += __shfl_xor(v, 16, 64);
        v += __shfl_xor(v, 32, 64);
        if (quad == 0) s_znorm[mw * ROWS_PER_WAVE + s * 16 + m16] = v;
    }
    __syncthreads();

    // ---- main loop over this half's 32 groups of 16 codes, 2x unrolled
    float bestv[NSUB][4];
    int besti[NSUB][4];
#pragma unroll
    for (int s = 0; s < NSUB; ++s)
#pragma unroll
        for (int r = 0; r < 4; ++r) {
            bestv[s][r] = FLT_MAX;
            besti[s][r] = 0;
        }

    // B layout (16x16x32): lane holds B[k=quad*8+j][n=lane&15]
    const _Float16* bhp = Ehi + (size_t)m16 * DIM + quad * 8;
    const _Float16* blp = Elo + (size_t)m16 * DIM + quad * 8;

    const int g0 = khalf * HGROUPS;
    const int gend = g0 + HGROUPS;

    f16x8 B0h[KSTEPS], B0l[KSTEPS], B1h[KSTEPS], B1l[KSTEPS];
#pragma unroll
    for (int ks = 0; ks < KSTEPS; ++ks) {
        B0h[ks] = *(const f16x8*)(bhp + (size_t)g0 * 16 * DIM + ks * 32);
        B0l[ks] = *(const f16x8*)(blp + (size_t)g0 * 16 * DIM + ks * 32);
    }

#define COMPUTE_GROUP(GIDX, BH, BL)                                                         \
    {                                                                                       \
        const int n = (GIDX)*16 + m16;                                                      \
        f32x4 acc_hh[NSUB], acc_c[NSUB];                                                    \
        _Pragma("unroll") for (int s = 0; s < NSUB; ++s) {                                  \
            acc_hh[s] = (f32x4){0.f, 0.f, 0.f, 0.f};                                        \
            acc_c[s] = (f32x4){0.f, 0.f, 0.f, 0.f};                                        \
        }                                                                                   \
        _Pragma("unroll") for (int ks = 0; ks < KSTEPS; ++ks) {                             \
            _Pragma("unroll") for (int s = 0; s < NSUB; ++s) {                              \
                acc_c[s] = __builtin_amdgcn_mfma_f32_16x16x32_f16(Ahi[s][ks], BL[ks],       \
                                                                  acc_c[s], 0, 0, 0);       \
                acc_c[s] = __builtin_amdgcn_mfma_f32_16x16x32_f16(Alo[s][ks], BH[ks],       \
                                                                  acc_c[s], 0, 0, 0);       \
                acc_hh[s] = __builtin_amdgcn_mfma_f32_16x16x32_f16(Ahi[s][ks], BH[ks],      \
                                                                   acc_hh[s], 0, 0, 0);     \
            }                                                                               \
        }                                                                                   \
        const float e = s_enorm[n];                                                         \
        _Pragma("unroll") for (int s = 0; s < NSUB; ++s) _Pragma("unroll")                  \
            for (int r = 0; r < 4; ++r) {                                                   \
                float d = (acc_hh[s][r] + acc_c[s][r]) + e;                                 \
                if (d < bestv[s][r]) { /* strict <, ascending g => first-index tie rule */  \
                    bestv[s][r] = d;                                                        \
                    besti[s][r] = n;                                                        \
                }                                                                           \
            }                                                                               \
    }

#define PREFETCH(GIDX, BH, BL)                                      \
    {                                                               \
        const size_t boff = (size_t)(GIDX)*16 * DIM;                \
        _Pragma("unroll") for (int ks = 0; ks < KSTEPS; ++ks) {     \
            BH[ks] = *(const f16x8*)(bhp + boff + ks * 32);         \
            BL[ks] = *(const f16x8*)(blp + boff + ks * 32);         \
        }                                                           \
    }

    for (int g = g0; g < gend; g += 2) {
        PREFETCH(g + 1, B1h, B1l)
        COMPUTE_GROUP(g, B0h, B0l)
        if (g + 2 < gend) PREFETCH(g + 2, B0h, B0l)
        COMPUTE_GROUP(g + 1, B1h, B1l)
    }
#undef COMPUTE_GROUP
#undef PREFETCH

    // ---- cross-lane argmin: each row's 32 candidate lanes (16 per K-half) -> LDS
#pragma unroll
    for (int s = 0; s < NSUB; ++s)
#pragma unroll
        for (int r = 0; r < 4; ++r) {
            const int row = mw * ROWS_PER_WAVE + s * 16 + quad * 4 + r;
            s_bv[row][khalf * 16 + m16] = bestv[s][r];
            s_bi[row][khalf * 16 + m16] = besti[s][r];
        }
    __syncthreads();

    float lp = 0.f;
    if (t < MTILE) {
        float bv = s_bv[t][0];
        int bi = s_bi[t][0];
#pragma unroll
        for (int j = 1; j < 32; ++j) {
            float v = s_bv[t][j];
            int i = s_bi[t][j];
            if (v < bv || (v == bv && i < bi)) {  // lexicographic: min val, min index
                bv = v;
                bi = i;
            }
        }
        s_ind[t] = bi;
        lp = s_znorm[t] + bv;  // ||z-E||^2 = ||z||^2 + (||E||^2 - 2 z.E)
    }
#pragma unroll
    for (int off = 32; off > 0; off >>= 1) lp += __shfl_down(lp, off, 64);
    if (lane == 0) s_wsum[wave] = lp;
    __syncthreads();
    if (t == 0) {
        float s = 0.f;
#pragma unroll
        for (int w = 0; w < 8; ++w) s += s_wsum[w];
        atomicAdd(loss, s * LOSS_SCALE);
    }

    // ---- gather-write z_q (STE forward == z_q), float4 coalesced, E is L2-hot
    const float4* E4 = (const float4*)E;
    float4* out4 = (float4*)(out + (size_t)blockIdx.x * (MTILE * DIM));
#pragma unroll
    for (int i = 0; i < (MTILE * DIM) / (512 * 4); ++i) {
        const int f = t + i * 512;  // float4 index within tile
        const int r = f >> 5;       // 32 float4 per row
        const int d = f & 31;
        out4[f] = E4[(size_t)s_ind[r] * 32 + d];
    }
}

extern "C" void kernel_launch(void* const* d_in, const int* in_sizes, int n_in,
                              void* d_out, int out_size, void* d_ws, size_t ws_size,
                              hipStream_t stream) {
    const float* z = (const float*)d_in[0];  // [BN,128] fp32
    const float* E = (const float*)d_in[1];  // [1024,128] fp32
    float* out = (float*)d_out;              // [BN*128] z_q + [1] loss
    float* loss = out + (size_t)(out_size - 1);
    _Float16* Ehi = (_Float16*)d_ws;                 // 256 KB
    _Float16* Elo = Ehi + (size_t)NCODES * DIM;      // 256 KB
    float* enorm = (float*)(Elo + (size_t)NCODES * DIM);  // 4 KB
    const int BN = in_sizes[0] / DIM;

    prep_kernel<<<NCODES, 128, 0, stream>>>(E, Ehi, Elo, enorm, loss);
    vq_kernel<<<BN / MTILE, 512, 0, stream>>>(z, Ehi, Elo, enorm, E, out, loss);
}

// Round 6
// 204.684 us; speedup vs baseline: 1.7587x; 1.7587x over previous
//
#include <hip/hip_runtime.h>
#include <hip/hip_bf16.h>
#include <cfloat>

// B=32, N=2048 -> BN=65536 rows, D=128, K=1024 codes
#define DIM 128
#define NCODES 1024
#define MTILE 64           // rows per block (2 row-waves x 32 rows; x2 K-halves = 4 waves)
#define ROWS_PER_WAVE 32
#define NSUB 2             // 16-row M-subtiles per wave
#define KSTEPS 4           // K=128 / 32
#define GROUPS (NCODES / 16)      // 64 groups of 16 codes
#define HGROUPS (GROUPS / 2)      // 32 groups per K-half
#define LOSS_SCALE (12.5f / 8388608.0f)

typedef _Float16 f16x8 __attribute__((ext_vector_type(8)));
typedef float f32x4 __attribute__((ext_vector_type(4)));

// prep: E (fp32) -> Ehi,Elo (f16 split) + enorm = ||E_k||^2; block 0 zeroes loss
__global__ __launch_bounds__(128) void prep_kernel(const float* __restrict__ E,
                                                   _Float16* __restrict__ Ehi,
                                                   _Float16* __restrict__ Elo,
                                                   float* __restrict__ enorm,
                                                   float* __restrict__ loss) {
    const int k = blockIdx.x;
    const int d = threadIdx.x;
    if (k == 0 && d == 0) *loss = 0.f;
    float e = E[k * DIM + d];
    _Float16 h = (_Float16)e;
    Ehi[k * DIM + d] = h;
    Elo[k * DIM + d] = (_Float16)(e - (float)h);
    float sq = e * e;
#pragma unroll
    for (int off = 32; off > 0; off >>= 1) sq += __shfl_down(sq, off, 64);
    __shared__ float s2[2];
    if ((d & 63) == 0) s2[d >> 6] = sq;
    __syncthreads();
    if (d == 0) enorm[k] = s2[0] + s2[1];
}

// Fused MFMA dist + argmin + gather + loss. 256 threads = 4 waves:
// wave = 2*khalf + mw; row-wave mw in {0,1} handles rows [mw*32, mw*32+32),
// K-half khalf in {0,1} handles codes [khalf*512, khalf*512+512).
// MTILE=64 -> grid 1024 blocks = 4 blocks/CU x 4 waves = 16 waves/CU (r4 was
// grid-capped at 8 waves/CU with all pipes <15% busy). Per-wave working set
// and inner loop are IDENTICAL to r4's proven 96-VGPR codegen.
// r5 lesson: 512-thread blocks + __launch_bounds__(512,4) made the compiler
// cap at 64 VGPRs (second arg treated as blocks/CU) -> 1 GB spill traffic.
// Stay on (256,2). r3 lesson: ping-pong B buffers must be statically named.
__global__ __launch_bounds__(256, 2) void vq_kernel(const float* __restrict__ z,
                                                    const _Float16* __restrict__ Ehi,
                                                    const _Float16* __restrict__ Elo,
                                                    const float* __restrict__ enorm,
                                                    const float* __restrict__ E,
                                                    float* __restrict__ out,
                                                    float* __restrict__ loss) {
    const int t = threadIdx.x;
    const int lane = t & 63;
    const int wave = t >> 6;
    const int mw = wave & 1;     // row-wave
    const int khalf = wave >> 1; // code-half
    const int m16 = lane & 15;   // A row within subtile / B,C code col
    const int quad = lane >> 4;  // k-group for A/B; row-group for C

    __shared__ float s_enorm[NCODES];
    __shared__ float s_znorm[MTILE];
    __shared__ float s_bv[MTILE][33];
    __shared__ int s_bi[MTILE][33];
    __shared__ int s_ind[MTILE];
    __shared__ float s_wsum[4];

    for (int i = t; i < NCODES; i += 256) s_enorm[i] = enorm[i];

    // ---- A fragments: wave's 32 rows, K=128, scaled by -2, f16 hi/lo split.
    // A layout (16x16x32): lane holds A[m=lane&15][k=quad*8+j], j=0..7.
    f16x8 Ahi[NSUB][KSTEPS], Alo[NSUB][KSTEPS];
    float znp[NSUB] = {0.f, 0.f};
    const int rowbase = blockIdx.x * MTILE + mw * ROWS_PER_WAVE;
#pragma unroll
    for (int s = 0; s < NSUB; ++s) {
        const int row = rowbase + s * 16 + m16;
        const float* zp = z + (size_t)row * DIM + quad * 8;
#pragma unroll
        for (int ks = 0; ks < KSTEPS; ++ks) {
            float4 v0 = *(const float4*)(zp + ks * 32);
            float4 v1 = *(const float4*)(zp + ks * 32 + 4);
            float zv[8] = {v0.x, v0.y, v0.z, v0.w, v1.x, v1.y, v1.z, v1.w};
#pragma unroll
            for (int j = 0; j < 8; ++j) {
                znp[s] = fmaf(zv[j], zv[j], znp[s]);
                float tt = -2.f * zv[j];
                _Float16 h = (_Float16)tt;
                Ahi[s][ks][j] = h;
                Alo[s][ks][j] = (_Float16)(tt - (float)h);
            }
        }
    }
    // znorm: sum the 4 k-quads. Both khalves write identical bits -> benign.
#pragma unroll
    for (int s = 0; s < NSUB; ++s) {
        float v = znp[s];
        v += __shfl_xor(v, 16, 64);
        v += __shfl_xor(v, 32, 64);
        if (quad == 0) s_znorm[mw * ROWS_PER_WAVE + s * 16 + m16] = v;
    }
    __syncthreads();

    // ---- main loop over this K-half's 32 groups of 16 codes, 2x unrolled
    float bestv[NSUB][4];
    int besti[NSUB][4];
#pragma unroll
    for (int s = 0; s < NSUB; ++s)
#pragma unroll
        for (int r = 0; r < 4; ++r) {
            bestv[s][r] = FLT_MAX;
            besti[s][r] = 0;
        }

    // B layout (16x16x32): lane holds B[k=quad*8+j][n=lane&15]
    const _Float16* bhp = Ehi + (size_t)m16 * DIM + quad * 8;
    const _Float16* blp = Elo + (size_t)m16 * DIM + quad * 8;

    const int g0 = khalf * HGROUPS;
    const int gend = g0 + HGROUPS;

    f16x8 B0h[KSTEPS], B0l[KSTEPS], B1h[KSTEPS], B1l[KSTEPS];
#pragma unroll
    for (int ks = 0; ks < KSTEPS; ++ks) {
        B0h[ks] = *(const f16x8*)(bhp + (size_t)g0 * 16 * DIM + ks * 32);
        B0l[ks] = *(const f16x8*)(blp + (size_t)g0 * 16 * DIM + ks * 32);
    }

#define COMPUTE_GROUP(GIDX, BH, BL)                                                         \
    {                                                                                       \
        const int n = (GIDX)*16 + m16;                                                      \
        f32x4 acc_hh[NSUB], acc_c[NSUB];                                                    \
        _Pragma("unroll") for (int s = 0; s < NSUB; ++s) {                                  \
            acc_hh[s] = (f32x4){0.f, 0.f, 0.f, 0.f};                                        \
            acc_c[s] = (f32x4){0.f, 0.f, 0.f, 0.f};                                        \
        }                                                                                   \
        _Pragma("unroll") for (int ks = 0; ks < KSTEPS; ++ks) {                             \
            _Pragma("unroll") for (int s = 0; s < NSUB; ++s) {                              \
                acc_c[s] = __builtin_amdgcn_mfma_f32_16x16x32_f16(Ahi[s][ks], BL[ks],       \
                                                                  acc_c[s], 0, 0, 0);       \
                acc_c[s] = __builtin_amdgcn_mfma_f32_16x16x32_f16(Alo[s][ks], BH[ks],       \
                                                                  acc_c[s], 0, 0, 0);       \
                acc_hh[s] = __builtin_amdgcn_mfma_f32_16x16x32_f16(Ahi[s][ks], BH[ks],      \
                                                                   acc_hh[s], 0, 0, 0);     \
            }                                                                               \
        }                                                                                   \
        const float e = s_enorm[n];                                                         \
        _Pragma("unroll") for (int s = 0; s < NSUB; ++s) _Pragma("unroll")                  \
            for (int r = 0; r < 4; ++r) {                                                   \
                float d = (acc_hh[s][r] + acc_c[s][r]) + e;                                 \
                if (d < bestv[s][r]) { /* strict <, ascending g => first-index tie rule */  \
                    bestv[s][r] = d;                                                        \
                    besti[s][r] = n;                                                        \
                }                                                                           \
            }                                                                               \
    }

#define PREFETCH(GIDX, BH, BL)                                      \
    {                                                               \
        const size_t boff = (size_t)(GIDX)*16 * DIM;                \
        _Pragma("unroll") for (int ks = 0; ks < KSTEPS; ++ks) {     \
            BH[ks] = *(const f16x8*)(bhp + boff + ks * 32);         \
            BL[ks] = *(const f16x8*)(blp + boff + ks * 32);         \
        }                                                           \
    }

    for (int g = g0; g < gend; g += 2) {
        PREFETCH(g + 1, B1h, B1l)
        COMPUTE_GROUP(g, B0h, B0l)
        if (g + 2 < gend) PREFETCH(g + 2, B0h, B0l)
        COMPUTE_GROUP(g + 1, B1h, B1l)
    }
#undef COMPUTE_GROUP
#undef PREFETCH

    // ---- cross-lane argmin: each row's 32 candidate lanes (16 per K-half) -> LDS
#pragma unroll
    for (int s = 0; s < NSUB; ++s)
#pragma unroll
        for (int r = 0; r < 4; ++r) {
            const int row = mw * ROWS_PER_WAVE + s * 16 + quad * 4 + r;
            s_bv[row][khalf * 16 + m16] = bestv[s][r];
            s_bi[row][khalf * 16 + m16] = besti[s][r];
        }
    __syncthreads();

    float lp = 0.f;
    if (t < MTILE) {
        float bv = s_bv[t][0];
        int bi = s_bi[t][0];
#pragma unroll
        for (int j = 1; j < 32; ++j) {
            float v = s_bv[t][j];
            int i = s_bi[t][j];
            if (v < bv || (v == bv && i < bi)) {  // lexicographic: min val, min index
                bv = v;
                bi = i;
            }
        }
        s_ind[t] = bi;
        lp = s_znorm[t] + bv;  // ||z-E||^2 = ||z||^2 + (||E||^2 - 2 z.E)
    }
#pragma unroll
    for (int off = 32; off > 0; off >>= 1) lp += __shfl_down(lp, off, 64);
    if (lane == 0) s_wsum[wave] = lp;
    __syncthreads();
    if (t == 0)
        atomicAdd(loss, (s_wsum[0] + s_wsum[1] + s_wsum[2] + s_wsum[3]) * LOSS_SCALE);

    // ---- gather-write z_q (STE forward == z_q), float4 coalesced, E is L2-hot
    const float4* E4 = (const float4*)E;
    float4* out4 = (float4*)(out + (size_t)blockIdx.x * (MTILE * DIM));
#pragma unroll
    for (int i = 0; i < (MTILE * DIM) / (256 * 4); ++i) {
        const int f = t + i * 256;  // float4 index within tile
        const int r = f >> 5;       // 32 float4 per row
        const int d = f & 31;
        out4[f] = E4[(size_t)s_ind[r] * 32 + d];
    }
}

extern "C" void kernel_launch(void* const* d_in, const int* in_sizes, int n_in,
                              void* d_out, int out_size, void* d_ws, size_t ws_size,
                              hipStream_t stream) {
    const float* z = (const float*)d_in[0];  // [BN,128] fp32
    const float* E = (const float*)d_in[1];  // [1024,128] fp32
    float* out = (float*)d_out;              // [BN*128] z_q + [1] loss
    float* loss = out + (size_t)(out_size - 1);
    _Float16* Ehi = (_Float16*)d_ws;                 // 256 KB
    _Float16* Elo = Ehi + (size_t)NCODES * DIM;      // 256 KB
    float* enorm = (float*)(Elo + (size_t)NCODES * DIM);  // 4 KB
    const int BN = in_sizes[0] / DIM;

    prep_kernel<<<NCODES, 128, 0, stream>>>(E, Ehi, Elo, enorm, loss);
    vq_kernel<<<BN / MTILE, 256, 0, stream>>>(z, Ehi, Elo, enorm, E, out, loss);
}

// Round 7
// 131.058 us; speedup vs baseline: 2.7467x; 1.5618x over previous
//
#include <hip/hip_runtime.h>
#include <hip/hip_bf16.h>
#include <cfloat>

// B=32, N=2048 -> BN=65536 rows, D=128, K=1024 codes
#define DIM 128
#define NCODES 1024
#define MTILE 128            // rows per block = 4 waves x 32 rows
#define ROWS_PER_WAVE 32
#define NSUB 2               // 16-row M-subtiles per wave
#define KSTEPS 4             // K=128 / 32
#define CODES_PER_STEP 32    // codes staged to LDS per step
#define NSTEPS (NCODES / CODES_PER_STEP)  // 32
#define BPITCH 136           // 128 + 8 f16 pad (272 B rows) -> conflict-free LDS
#define LOSS_SCALE (12.5f / 8388608.0f)

typedef _Float16 f16x8 __attribute__((ext_vector_type(8)));
typedef float f32x4 __attribute__((ext_vector_type(4)));

// prep: E (fp32) -> Ehi,Elo (f16 split) + enorm = ||E_k||^2; block 0 zeroes loss
__global__ __launch_bounds__(128) void prep_kernel(const float* __restrict__ E,
                                                   _Float16* __restrict__ Ehi,
                                                   _Float16* __restrict__ Elo,
                                                   float* __restrict__ enorm,
                                                   float* __restrict__ loss) {
    const int k = blockIdx.x;
    const int d = threadIdx.x;
    if (k == 0 && d == 0) *loss = 0.f;
    float e = E[k * DIM + d];
    _Float16 h = (_Float16)e;
    Ehi[k * DIM + d] = h;
    Elo[k * DIM + d] = (_Float16)(e - (float)h);
    float sq = e * e;
#pragma unroll
    for (int off = 32; off > 0; off >>= 1) sq += __shfl_down(sq, off, 64);
    __shared__ float s2[2];
    if ((d & 63) == 0) s2[d >> 6] = sq;
    __syncthreads();
    if (d == 0) enorm[k] = s2[0] + s2[1];
}

// Fused MFMA dist + argmin + gather + loss, LDS-staged B.
// r2/r4/r6 all plateaued at ~140 us with every pipe <15% busy: each wave
// streamed the full 512 KB codebook through L1 (65k line-fetches/CU at ~250 cyc
// L2 latency = L1 miss-queue wall). Fix: stage each 32-code B tile (hi+lo,
// 16 KB) into LDS once per block, shared by all 4 waves (4x line-traffic cut);
// fragment reads become ds_read_b128 at ~85 B/cyc/CU. Double-buffered with one
// barrier per step. Padded pitch (272 B) keeps LDS conflict-free.
// Argmin uses in-wave shfl_xor butterflies (lexicographic (val,idx) == jnp
// first-index rule) instead of LDS arrays.
// r3 lesson: no runtime-indexed register arrays. r5 lesson: stay on (256,2).
__global__ __launch_bounds__(256, 2) void vq_kernel(const float* __restrict__ z,
                                                    const _Float16* __restrict__ Ehi,
                                                    const _Float16* __restrict__ Elo,
                                                    const float* __restrict__ enorm,
                                                    const float* __restrict__ E,
                                                    float* __restrict__ out,
                                                    float* __restrict__ loss) {
    const int t = threadIdx.x;
    const int lane = t & 63;
    const int wave = t >> 6;     // row-wave: rows [wave*32, wave*32+32)
    const int m16 = lane & 15;   // A row within subtile / B,C code col
    const int quad = lane >> 4;  // k-group for A/B; row-group for C

    __shared__ _Float16 s_bh[2][CODES_PER_STEP * BPITCH];  // 17408 B
    __shared__ _Float16 s_bl[2][CODES_PER_STEP * BPITCH];  // 17408 B
    __shared__ float s_enorm[NCODES];                      // 4096 B
    __shared__ float s_znorm[MTILE];
    __shared__ int s_ind[MTILE];
    __shared__ float s_wsum[4];

    for (int i = t; i < NCODES; i += 256) s_enorm[i] = enorm[i];

    // ---- A fragments: wave's 32 rows, K=128, scaled by -2, f16 hi/lo split.
    // A layout (16x16x32): lane holds A[m=lane&15][k=quad*8+j], j=0..7.
    f16x8 Ahi[NSUB][KSTEPS], Alo[NSUB][KSTEPS];
    float znp[NSUB] = {0.f, 0.f};
    const int rowbase = blockIdx.x * MTILE + wave * ROWS_PER_WAVE;
#pragma unroll
    for (int s = 0; s < NSUB; ++s) {
        const int row = rowbase + s * 16 + m16;
        const float* zp = z + (size_t)row * DIM + quad * 8;
#pragma unroll
        for (int ks = 0; ks < KSTEPS; ++ks) {
            float4 v0 = *(const float4*)(zp + ks * 32);
            float4 v1 = *(const float4*)(zp + ks * 32 + 4);
            float zv[8] = {v0.x, v0.y, v0.z, v0.w, v1.x, v1.y, v1.z, v1.w};
#pragma unroll
            for (int j = 0; j < 8; ++j) {
                znp[s] = fmaf(zv[j], zv[j], znp[s]);
                float tt = -2.f * zv[j];
                _Float16 h = (_Float16)tt;
                Ahi[s][ks][j] = h;
                Alo[s][ks][j] = (_Float16)(tt - (float)h);
            }
        }
    }
    // znorm per row -> LDS (consumed after loop; loop barriers order it)
#pragma unroll
    for (int s = 0; s < NSUB; ++s) {
        float v = znp[s];
        v += __shfl_xor(v, 16, 64);
        v += __shfl_xor(v, 32, 64);
        if (quad == 0) s_znorm[wave * ROWS_PER_WAVE + s * 16 + m16] = v;
    }

    float bestv[NSUB][4];
    int besti[NSUB][4];
#pragma unroll
    for (int s = 0; s < NSUB; ++s)
#pragma unroll
        for (int r = 0; r < 4; ++r) {
            bestv[s][r] = FLT_MAX;
            besti[s][r] = 0;
        }

    // Stage step ST's 32-code tile (hi+lo) into LDS buffer B.
    // 1024 16B-chunks (512 hi + 512 lo) / 256 threads = 4 per thread.
    // Global reads: consecutive t -> consecutive 16 B (coalesced).
#define STAGE(ST, B)                                                    \
    {                                                                   \
        const int j0 = t, j1 = t + 256;                                 \
        const int n0 = j0 >> 4, c0 = j0 & 15;                           \
        const int n1 = j1 >> 4, c1 = j1 & 15;                           \
        const size_t g0o = (size_t)(ST)*4096 + n0 * 128 + c0 * 8;       \
        const size_t g1o = (size_t)(ST)*4096 + n1 * 128 + c1 * 8;       \
        f16x8 h0 = *(const f16x8*)(Ehi + g0o);                          \
        f16x8 h1 = *(const f16x8*)(Ehi + g1o);                          \
        f16x8 q0 = *(const f16x8*)(Elo + g0o);                          \
        f16x8 q1 = *(const f16x8*)(Elo + g1o);                          \
        *(f16x8*)&s_bh[B][n0 * BPITCH + c0 * 8] = h0;                   \
        *(f16x8*)&s_bh[B][n1 * BPITCH + c1 * 8] = h1;                   \
        *(f16x8*)&s_bl[B][n0 * BPITCH + c0 * 8] = q0;                   \
        *(f16x8*)&s_bl[B][n1 * BPITCH + c1 * 8] = q1;                   \
    }

    STAGE(0, 0)
    __syncthreads();

    int buf = 0;
    for (int st = 0; st < NSTEPS; ++st) {
        if (st + 1 < NSTEPS) STAGE(st + 1, buf ^ 1)  // overlap with compute below
        const _Float16* bh = s_bh[buf];
        const _Float16* bl = s_bl[buf];
#pragma unroll
        for (int u = 0; u < 2; ++u) {  // two 16-code subgroups
            const int off = (u * 16 + m16) * BPITCH + quad * 8;
            f16x8 Bh[KSTEPS], Bl[KSTEPS];
#pragma unroll
            for (int ks = 0; ks < KSTEPS; ++ks) {
                Bh[ks] = *(const f16x8*)(bh + off + ks * 32);
                Bl[ks] = *(const f16x8*)(bl + off + ks * 32);
            }
            f32x4 acc_hh[NSUB], acc_c[NSUB];
#pragma unroll
            for (int s = 0; s < NSUB; ++s) {
                acc_hh[s] = (f32x4){0.f, 0.f, 0.f, 0.f};
                acc_c[s] = (f32x4){0.f, 0.f, 0.f, 0.f};
            }
#pragma unroll
            for (int ks = 0; ks < KSTEPS; ++ks)
#pragma unroll
                for (int s = 0; s < NSUB; ++s) {
                    acc_c[s] = __builtin_amdgcn_mfma_f32_16x16x32_f16(Ahi[s][ks], Bl[ks], acc_c[s], 0, 0, 0);
                    acc_c[s] = __builtin_amdgcn_mfma_f32_16x16x32_f16(Alo[s][ks], Bh[ks], acc_c[s], 0, 0, 0);
                    acc_hh[s] = __builtin_amdgcn_mfma_f32_16x16x32_f16(Ahi[s][ks], Bh[ks], acc_hh[s], 0, 0, 0);
                }
            const int n = st * CODES_PER_STEP + u * 16 + m16;
            const float e = s_enorm[n];
            // C layout: col = lane&15 (code), row = quad*4 + r
#pragma unroll
            for (int s = 0; s < NSUB; ++s)
#pragma unroll
                for (int r = 0; r < 4; ++r) {
                    float d = (acc_hh[s][r] + acc_c[s][r]) + e;
                    if (d < bestv[s][r]) {  // strict <, ascending n per lane => first-index
                        bestv[s][r] = d;
                        besti[s][r] = n;
                    }
                }
        }
        __syncthreads();  // staged st+1 visible; buf safe to overwrite at st+2
        buf ^= 1;
    }
#undef STAGE

    // ---- in-wave argmin across the 16 m16-lanes (xor butterflies stay in-quad;
    // lexicographic (v,i) merge == global first-index rule)
#pragma unroll
    for (int s = 0; s < NSUB; ++s)
#pragma unroll
        for (int r = 0; r < 4; ++r) {
            float v = bestv[s][r];
            int i = besti[s][r];
#pragma unroll
            for (int m = 1; m <= 8; m <<= 1) {
                float ov = __shfl_xor(v, m, 64);
                int oi = __shfl_xor(i, m, 64);
                if (ov < v || (ov == v && oi < i)) {
                    v = ov;
                    i = oi;
                }
            }
            bestv[s][r] = v;
            besti[s][r] = i;
        }

    float lp = 0.f;
    if (m16 == 0) {  // one winner lane per quad; owns rows quad*4+r (+s*16)
#pragma unroll
        for (int s = 0; s < NSUB; ++s)
#pragma unroll
            for (int r = 0; r < 4; ++r) {
                const int row = wave * ROWS_PER_WAVE + s * 16 + quad * 4 + r;
                s_ind[row] = besti[s][r];
                lp += s_znorm[row] + bestv[s][r];  // ||z-E||^2 = ||z||^2 + dist'
            }
    }
    lp += __shfl_xor(lp, 16, 64);  // lanes {0,16,32,48} hold partials
    lp += __shfl_xor(lp, 32, 64);
    if (lane == 0) s_wsum[wave] = lp;
    __syncthreads();
    if (t == 0)
        atomicAdd(loss, (s_wsum[0] + s_wsum[1] + s_wsum[2] + s_wsum[3]) * LOSS_SCALE);

    // ---- gather-write z_q (STE forward == z_q), float4 coalesced, E is L2-hot
    const float4* E4 = (const float4*)E;
    float4* out4 = (float4*)(out + (size_t)blockIdx.x * (MTILE * DIM));
#pragma unroll
    for (int i = 0; i < (MTILE * DIM) / (256 * 4); ++i) {
        const int f = t + i * 256;  // float4 index within tile
        const int r = f >> 5;       // 32 float4 per row
        const int d = f & 31;
        out4[f] = E4[(size_t)s_ind[r] * 32 + d];
    }
}

extern "C" void kernel_launch(void* const* d_in, const int* in_sizes, int n_in,
                              void* d_out, int out_size, void* d_ws, size_t ws_size,
                              hipStream_t stream) {
    const float* z = (const float*)d_in[0];  // [BN,128] fp32
    const float* E = (const float*)d_in[1];  // [1024,128] fp32
    float* out = (float*)d_out;              // [BN*128] z_q + [1] loss
    float* loss = out + (size_t)(out_size - 1);
    _Float16* Ehi = (_Float16*)d_ws;                 // 256 KB
    _Float16* Elo = Ehi + (size_t)NCODES * DIM;      // 256 KB
    float* enorm = (float*)(Elo + (size_t)NCODES * DIM);  // 4 KB
    const int BN = in_sizes[0] / DIM;

    prep_kernel<<<NCODES, 128, 0, stream>>>(E, Ehi, Elo, enorm, loss);
    vq_kernel<<<BN / MTILE, 256, 0, stream>>>(z, Ehi, Elo, enorm, E, out, loss);
}